// Round 1
// baseline (635.041 us; speedup 1.0000x reference)
//
#include <hip/hip_runtime.h>
#include <hip/hip_bf16.h>
#include <math.h>

// VQEmbeddingGSSoft fused kernel for MI355X (gfx950).
// B=32, C=D=64, T=4096, M=512, temperature=0.5.
// Outputs: quantized (B,T,64) [8388608 floats], KL [1], perplexity [1].
//
// Algebra: softmax over M is shift-invariant per row, so logits are computed
// as l_m = 2*x.w_m - ||w_m||^2 (the ||x||^2 term cancels and is never computed).
// Softmax maxes are replaced by a fixed safe bias (gumbel<=16.64, |l|<=~0.3):
// s = exp(2l + (2g - 36)) never overflows/underflows in fp32.

#define LOG_M 6.2383246250395075f   // ln(512)

typedef __attribute__((ext_vector_type(8))) __bf16 bf16x8;
typedef __attribute__((ext_vector_type(4))) float  floatx4;

__device__ __forceinline__ unsigned int f2bf_bits(float f) {
    unsigned int b = __builtin_bit_cast(unsigned int, f);
    return (b + 0x7fffu + ((b >> 16) & 1u)) >> 16;   // RNE bf16
}
__device__ __forceinline__ float bf2f(unsigned int bits16) {
    return __builtin_bit_cast(float, bits16 << 16);
}

// ---------------- prep: W fp32 -> bf16 (row-major + transposed) + ||w||^2 ----
__global__ void vq_prep(const float* __restrict__ W,
                        unsigned short* __restrict__ Wbf,
                        unsigned short* __restrict__ WTbf,
                        float* __restrict__ wn2)
{
    const int m = blockIdx.x * 256 + threadIdx.x;   // 0..511
    float acc = 0.f;
    #pragma unroll 8
    for (int d = 0; d < 64; ++d) {
        float v = W[m * 64 + d];
        acc = fmaf(v, v, acc);
        unsigned short h = (unsigned short)f2bf_bits(v);
        Wbf[m * 64 + d]  = h;
        WTbf[d * 512 + m] = h;
    }
    wn2[m] = acc;
}

// ---------------- main fused kernel ----------------
// grid = 2048 blocks (32 b * 64 t-tiles of 64), block = 256 (4 waves).
// Wave w handles 16 t-values (t0+16w .. +16) x all 512 codes.
__global__ __launch_bounds__(256, 2) void vq_main(
    const float* __restrict__ x, const float* __restrict__ u,
    const unsigned short* __restrict__ Wbf, const unsigned short* __restrict__ WTbf,
    const float* __restrict__ wn2, float* __restrict__ out,
    float* __restrict__ avg_g, float* __restrict__ kl_g)
{
    __shared__ __align__(16) unsigned short xs[64][72];     // x tile, bf16, [t][d], padded
    __shared__ __align__(16) unsigned short sbuf[4][16][40];// per-wave S chunk [t][32m], padded
    __shared__ float avg_lds[512];

    const int tid  = threadIdx.x;
    const int bid  = blockIdx.x;
    const int b    = bid >> 6;
    const int t0   = (bid & 63) << 6;
    const int w    = tid >> 6;
    const int lane = tid & 63;
    const int ln   = lane & 15;   // n index (t within wave tile)
    const int q    = lane >> 4;   // quad

    avg_lds[tid]       = 0.0f;
    avg_lds[tid + 256] = 0.0f;

    // stage x tile: xs[t][d] = bf16(x[b][d][t0+t])  (coalesced along t)
    #pragma unroll
    for (int k2 = 0; k2 < 16; ++k2) {
        int idx = k2 * 256 + tid;
        int d = idx >> 6, t = idx & 63;
        float v = x[((size_t)(b * 64 + d)) * 4096 + (size_t)(t0 + t)];
        xs[t][d] = (unsigned short)f2bf_bits(v);
    }
    __syncthreads();

    const int tg = t0 + 16 * w + ln;   // this lane's global t

    // ---- GEMM1: l[m][t] = 2*(W @ x_col) - ||w||^2, packed bf16 in regs ----
    // A = W (M=code m, K=d): A[m=ln][k=q*8+j]; B = x (K=d, N=t): B[k=q*8+j][n=ln]
    bf16x8 xb0 = *(const bf16x8*)&xs[16 * w + ln][q * 8];
    bf16x8 xb1 = *(const bf16x8*)&xs[16 * w + ln][32 + q * 8];

    unsigned int lpk[64];   // 128 logits / lane, packed 2x bf16
    #pragma unroll
    for (int mt = 0; mt < 32; ++mt) {
        const unsigned short* wrow = Wbf + (size_t)(16 * mt + ln) * 64 + q * 8;
        bf16x8 a0 = *(const bf16x8*)(wrow);
        bf16x8 a1 = *(const bf16x8*)(wrow + 32);
        floatx4 acc = 0.0f;
        acc = __builtin_amdgcn_mfma_f32_16x16x32_bf16(a0, xb0, acc, 0, 0, 0);
        acc = __builtin_amdgcn_mfma_f32_16x16x32_bf16(a1, xb1, acc, 0, 0, 0);
        // C/D layout: n = ln, m = 16*mt + 4*q + r
        const float4 wv = *(const float4*)(wn2 + 16 * mt + 4 * q);
        float l0 = fmaf(2.0f, acc[0], -wv.x);
        float l1 = fmaf(2.0f, acc[1], -wv.y);
        float l2 = fmaf(2.0f, acc[2], -wv.z);
        float l3 = fmaf(2.0f, acc[3], -wv.w);
        lpk[2 * mt]     = f2bf_bits(l0) | (f2bf_bits(l1) << 16);
        lpk[2 * mt + 1] = f2bf_bits(l2) | (f2bf_bits(l3) << 16);
    }

    // ---- load u (32 float4 in flight), then gumbel in-place: gs = 2g - 36 ----
    float gs[128];
    const float* ub = u + ((size_t)(b * 4096 + tg)) * 512 + 4 * q;
    #pragma unroll
    for (int i = 0; i < 32; ++i) {
        float4 uv = *(const float4*)(ub + 16 * i);
        gs[4 * i + 0] = uv.x; gs[4 * i + 1] = uv.y;
        gs[4 * i + 2] = uv.z; gs[4 * i + 3] = uv.w;
    }
    #pragma unroll
    for (int j = 0; j < 128; ++j) {
        float uu = fmaxf(gs[j], 1e-9f);
        // inner log: accurate near 1 via log1p poly (|z|<=0.25), HW log otherwise
        float z = uu - 1.0f;
        float p = fmaf(z, -0.125f, 0.14285715f);
        p = fmaf(z, p, -0.16666667f);
        p = fmaf(z, p, 0.2f);
        p = fmaf(z, p, -0.25f);
        p = fmaf(z, p, 0.33333334f);
        p = fmaf(z, p, -0.5f);
        p = fmaf(z, p, 1.0f);
        float il = (uu > 0.75f) ? (z * p) : __logf(uu);
        gs[j] = fmaf(-2.0f, __logf(-il), -36.0f);   // 2*gumbel - 36
    }

    // ---- fused pass: probs-softmax stats (tau=1) + unnormalized samples ----
    float T1 = 0.f, T2 = 0.f, Zg = 0.f;
    #pragma unroll
    for (int i = 0; i < 32; ++i) {
        unsigned int p0 = lpk[2 * i], p1 = lpk[2 * i + 1];
        float l0 = bf2f(p0 & 0xffffu), l1 = bf2f(p0 >> 16);
        float l2 = bf2f(p1 & 0xffffu), l3 = bf2f(p1 >> 16);
        float e0 = __expf(l0), e1 = __expf(l1), e2 = __expf(l2), e3 = __expf(l3);
        T1 += e0 + e1 + e2 + e3;
        T2 = fmaf(l0, e0, T2); T2 = fmaf(l1, e1, T2);
        T2 = fmaf(l2, e2, T2); T2 = fmaf(l3, e3, T2);
        float s0 = __expf(fmaf(2.0f, l0, gs[4 * i + 0]));
        float s1 = __expf(fmaf(2.0f, l1, gs[4 * i + 1]));
        float s2 = __expf(fmaf(2.0f, l2, gs[4 * i + 2]));
        float s3 = __expf(fmaf(2.0f, l3, gs[4 * i + 3]));
        gs[4 * i + 0] = s0; gs[4 * i + 1] = s1;
        gs[4 * i + 2] = s2; gs[4 * i + 3] = s3;
        Zg += s0 + s1 + s2 + s3;
    }
    // codes for a given t live in lanes {t, t+16, t+32, t+48}
    T1 += __shfl_xor(T1, 16); T1 += __shfl_xor(T1, 32);
    T2 += __shfl_xor(T2, 16); T2 += __shfl_xor(T2, 32);
    Zg += __shfl_xor(Zg, 16); Zg += __shfl_xor(Zg, 32);

    // KL(t) = sum_m p*(logp + logM) = T2/T1 - ln(T1) + ln(M)  (accurate logf)
    float klw = T2 / T1 - logf(T1) + LOG_M;
    klw += __shfl_xor(klw, 1);  klw += __shfl_xor(klw, 2);
    klw += __shfl_xor(klw, 4);  klw += __shfl_xor(klw, 8);
    klw += __shfl_xor(klw, 16); klw += __shfl_xor(klw, 32);
    if (lane == 0) atomicAdd(kl_g, 0.25f * klw);   // each t counted 4x (quad dup)

    const float invZ = 1.0f / Zg;

    // ---- GEMM2: Q^T[d][t] = W^T @ S, K=512 in 16 chunks of 32 ----
    floatx4 C2[4];
    #pragma unroll
    for (int dt = 0; dt < 4; ++dt) C2[dt] = 0.0f;

    #pragma unroll
    for (int kk = 0; kk < 16; ++kk) {
        #pragma unroll
        for (int ii = 0; ii < 2; ++ii) {
            const int i = 2 * kk + ii;   // m = 16*i + 4*q + r
            float s0 = gs[4*i+0] * invZ, s1 = gs[4*i+1] * invZ;
            float s2 = gs[4*i+2] * invZ, s3 = gs[4*i+3] * invZ;
            // avg_probs: reduce over the 16 t's of this wave (lanes sharing q)
            float v0 = s0, v1 = s1, v2 = s2, v3 = s3;
            v0 += __shfl_xor(v0,1); v0 += __shfl_xor(v0,2); v0 += __shfl_xor(v0,4); v0 += __shfl_xor(v0,8);
            v1 += __shfl_xor(v1,1); v1 += __shfl_xor(v1,2); v1 += __shfl_xor(v1,4); v1 += __shfl_xor(v1,8);
            v2 += __shfl_xor(v2,1); v2 += __shfl_xor(v2,2); v2 += __shfl_xor(v2,4); v2 += __shfl_xor(v2,8);
            v3 += __shfl_xor(v3,1); v3 += __shfl_xor(v3,2); v3 += __shfl_xor(v3,4); v3 += __shfl_xor(v3,8);
            if (ln == 0) {
                atomicAdd(&avg_lds[16*i + 4*q + 0], v0);
                atomicAdd(&avg_lds[16*i + 4*q + 1], v1);
                atomicAdd(&avg_lds[16*i + 4*q + 2], v2);
                atomicAdd(&avg_lds[16*i + 4*q + 3], v3);
            }
            // pack normalized samples to bf16 into wave-private LDS: sbuf[t][m-32kk]
            uint2 pk;
            pk.x = f2bf_bits(s0) | (f2bf_bits(s1) << 16);
            pk.y = f2bf_bits(s2) | (f2bf_bits(s3) << 16);
            *(uint2*)&sbuf[w][ln][16 * ii + 4 * q] = pk;
        }
        // cross-lane LDS RAW within the wave: drain DS queue before frag read
        __asm__ volatile("s_waitcnt lgkmcnt(0)" ::: "memory");
        // B-frag: B[k = q*8+j][n = ln] = S[32kk + q*8+j][t]
        bf16x8 sb = *(const bf16x8*)&sbuf[w][ln][8 * q];
        #pragma unroll
        for (int dt = 0; dt < 4; ++dt) {
            // A-frag: A[d = 16dt+ln][k = 32kk + q*8+j] = W^T (m-contiguous)
            bf16x8 a = *(const bf16x8*)(WTbf + (size_t)(16 * dt + ln) * 512 + 32 * kk + 8 * q);
            C2[dt] = __builtin_amdgcn_mfma_f32_16x16x32_bf16(a, sb, C2[dt], 0, 0, 0);
        }
    }

    // ---- store quantized: lane holds d = 16*dt + 4*q + r at its t ----
    float* op = out + ((size_t)(b * 4096 + tg)) * 64 + 4 * q;
    #pragma unroll
    for (int dt = 0; dt < 4; ++dt)
        *(floatx4*)(op + 16 * dt) = C2[dt];

    __syncthreads();
    atomicAdd(&avg_g[tid],       avg_lds[tid]);
    atomicAdd(&avg_g[tid + 256], avg_lds[tid + 256]);
}

// ---------------- finalize: KL mean + perplexity ----------------
__global__ void vq_fin(const float* __restrict__ avg_g, const float* __restrict__ kl_g,
                       float* __restrict__ out)
{
    const int lane = threadIdx.x;   // 64 threads
    float acc = 0.f;
    #pragma unroll
    for (int k = 0; k < 8; ++k) {
        float a = avg_g[lane * 8 + k] * (1.0f / 131072.0f);
        acc += a * logf(a + 1e-10f);
    }
    acc += __shfl_xor(acc, 1);  acc += __shfl_xor(acc, 2);
    acc += __shfl_xor(acc, 4);  acc += __shfl_xor(acc, 8);
    acc += __shfl_xor(acc, 16); acc += __shfl_xor(acc, 32);
    if (lane == 0) {
        out[8388608] = kl_g[0] * (1.0f / 32.0f);   // mean over B
        out[8388609] = expf(-acc);
    }
}

extern "C" void kernel_launch(void* const* d_in, const int* in_sizes, int n_in,
                              void* d_out, int out_size, void* d_ws, size_t ws_size,
                              hipStream_t stream)
{
    const float* x = (const float*)d_in[0];   // (32, 64, 4096)
    const float* u = (const float*)d_in[1];   // (32, 4096, 512)
    const float* W = (const float*)d_in[2];   // (512, 64)
    float* out = (float*)d_out;

    char* ws = (char*)d_ws;
    unsigned short* Wbf  = (unsigned short*)(ws);            // 65536 B
    unsigned short* WTbf = (unsigned short*)(ws + 65536);    // 65536 B
    float* wn2   = (float*)(ws + 131072);                    // 2048 B
    float* avg_g = (float*)(ws + 133120);                    // 2048 B
    float* kl_g  = (float*)(ws + 135168);                    // 4 B

    // zero the accumulators (ws is poisoned to 0xAA before every launch)
    (void)hipMemsetAsync(ws + 133120, 0, 2048 + 64, stream);

    vq_prep<<<dim3(2),    dim3(256), 0, stream>>>(W, Wbf, WTbf, wn2);
    vq_main<<<dim3(2048), dim3(256), 0, stream>>>(x, u, Wbf, WTbf, wn2, out, avg_g, kl_g);
    vq_fin <<<dim3(1),    dim3(64),  0, stream>>>(avg_g, kl_g, out);
}

// Round 2
// 545.502 us; speedup vs baseline: 1.1641x; 1.1641x over previous
//
#include <hip/hip_runtime.h>
#include <hip/hip_bf16.h>
#include <math.h>

// VQEmbeddingGSSoft fused kernel for MI355X (gfx950).
// B=32, C=D=64, T=4096, M=512, temperature=0.5.
// Outputs: quantized (B,T,64) [8388608 floats], KL [1], perplexity [1].
//
// Algebra:
//  - softmax over M is shift-invariant, so l_m = 2*x.w_m - ||w_m||^2
//    (the ||x||^2 term cancels and is never computed).
//  - fixed safe bias instead of max-pass: s = exp(2l + 2g - 36) with
//    g = -log(-log u) <= 16.64, |l| <= ~0.3 -> never overflows in fp32.
//  - transcendental elimination: s = (e^l / log u)^2 * e^-36, reusing
//    e^l (needed for the KL softmax stats). One exp + one log per element.
//  - softmax normalization (1/Z per t) is deferred to the GEMM2 epilogue:
//    the MFMA C-layout keeps each lane's outputs at a single t.

#define LOG_M   6.2383246250395075f   // ln(512)
#define EXPM36  2.3195228e-16f        // e^-36

typedef __attribute__((ext_vector_type(8))) __bf16 bf16x8;
typedef __attribute__((ext_vector_type(4))) float  floatx4;

__device__ __forceinline__ unsigned int f2bf_bits(float f) {
    unsigned int b = __builtin_bit_cast(unsigned int, f);
    return (b + 0x7fffu + ((b >> 16) & 1u)) >> 16;   // RNE bf16
}
__device__ __forceinline__ float bf2f(unsigned int bits16) {
    return __builtin_bit_cast(float, bits16 << 16);
}

// ---------------- prep: W fp32 -> bf16 (row-major + transposed) + ||w||^2 ----
__global__ void vq_prep(const float* __restrict__ W,
                        unsigned short* __restrict__ Wbf,
                        unsigned short* __restrict__ WTbf,
                        float* __restrict__ wn2)
{
    const int m = blockIdx.x * 256 + threadIdx.x;   // 0..511
    float acc = 0.f;
    #pragma unroll 8
    for (int d = 0; d < 64; ++d) {
        float v = W[m * 64 + d];
        acc = fmaf(v, v, acc);
        unsigned short h = (unsigned short)f2bf_bits(v);
        Wbf[m * 64 + d]  = h;
        WTbf[d * 512 + m] = h;
    }
    wn2[m] = acc;
}

// ---------------- main fused kernel ----------------
// grid = 2048 blocks (32 b * 64 t-tiles of 64), block = 256 (4 waves).
// Wave w handles 16 t-values (t0+16w .. +16) x all 512 codes.
// launch_bounds(256,3): cap ~168 VGPR, 12 waves/CU, no spill (spk[64]+~80 temps).
__global__ __launch_bounds__(256, 3) void vq_main(
    const float* __restrict__ x, const float* __restrict__ u,
    const unsigned short* __restrict__ Wbf, const unsigned short* __restrict__ WTbf,
    const float* __restrict__ wn2, float* __restrict__ out,
    float* __restrict__ avg_g, float* __restrict__ kl_g)
{
    __shared__ __align__(16) unsigned short xs[64][72];     // x tile, bf16, [t][d], padded
    __shared__ __align__(16) unsigned short sbuf[4][16][40];// per-wave S chunk [t][32m], padded
    __shared__ float avg_lds[512];

    const int tid  = threadIdx.x;
    const int bid  = blockIdx.x;
    const int b    = bid >> 6;
    const int t0   = (bid & 63) << 6;
    const int w    = tid >> 6;
    const int lane = tid & 63;
    const int ln   = lane & 15;   // n index (t within wave tile)
    const int q    = lane >> 4;   // quad

    avg_lds[tid]       = 0.0f;
    avg_lds[tid + 256] = 0.0f;

    // stage x tile: xs[t][d] = bf16(x[b][d][t0+t])  (coalesced along t)
    #pragma unroll
    for (int k2 = 0; k2 < 16; ++k2) {
        int idx = k2 * 256 + tid;
        int d = idx >> 6, t = idx & 63;
        float v = x[((size_t)(b * 64 + d)) * 4096 + (size_t)(t0 + t)];
        xs[t][d] = (unsigned short)f2bf_bits(v);
    }
    __syncthreads();

    const int tg = t0 + 16 * w + ln;   // this lane's global t

    // B-frag of GEMM1 (x tile): B[k=d=q*8+j][n=t=ln]
    bf16x8 xb0 = *(const bf16x8*)&xs[16 * w + ln][q * 8];
    bf16x8 xb1 = *(const bf16x8*)&xs[16 * w + ln][32 + q * 8];

    // ---- fused: logits (MFMA) + u load + gumbel + unnormalized sample ----
    unsigned int spk[64];   // 128 samples / lane, packed 2x bf16 (unnormalized)
    float T1 = 0.f, T2 = 0.f, Zg = 0.f;
    const float* ub = u + ((size_t)(b * 4096 + tg)) * 512 + 4 * q;

    #pragma unroll 4
    for (int i = 0; i < 32; ++i) {
        // A-frag: W rows m = 16*i + ln, k = d = q*8+j
        const unsigned short* wrow = Wbf + (size_t)(16 * i + ln) * 64 + q * 8;
        bf16x8 a0 = *(const bf16x8*)(wrow);
        bf16x8 a1 = *(const bf16x8*)(wrow + 32);
        float4 uv = *(const float4*)(ub + 16 * i);
        const float4 wv = *(const float4*)(wn2 + 16 * i + 4 * q);

        floatx4 acc = 0.0f;
        acc = __builtin_amdgcn_mfma_f32_16x16x32_bf16(a0, xb0, acc, 0, 0, 0);
        acc = __builtin_amdgcn_mfma_f32_16x16x32_bf16(a1, xb1, acc, 0, 0, 0);
        // C/D layout: n = ln (t), m = 16*i + 4*q + r

        float sr[4];
        const float ua[4] = {uv.x, uv.y, uv.z, uv.w};
        const float wa[4] = {wv.x, wv.y, wv.z, wv.w};
        #pragma unroll
        for (int r = 0; r < 4; ++r) {
            float l = fmaf(2.0f, acc[r], -wa[r]);
            float e = __expf(l);
            T1 += e;
            T2 = fmaf(l, e, T2);
            float uu = fmaxf(ua[r], 1e-9f);
            // inner log: accurate near 1 via log1p poly (|z|<=0.25), HW log otherwise
            float z = uu - 1.0f;
            float p = fmaf(z, -0.125f, 0.14285715f);
            p = fmaf(z, p, -0.16666667f);
            p = fmaf(z, p, 0.2f);
            p = fmaf(z, p, -0.25f);
            p = fmaf(z, p, 0.33333334f);
            p = fmaf(z, p, -0.5f);
            p = fmaf(z, p, 1.0f);
            float il = (uu > 0.75f) ? (z * p) : __logf(uu);   // log(u) < 0
            float rr = e * __builtin_amdgcn_rcpf(il);          // e^l / log(u)
            float s = (rr * rr) * EXPM36;                      // exp(2l + 2g - 36)
            Zg += s;
            sr[r] = s;
        }
        spk[2 * i]     = f2bf_bits(sr[0]) | (f2bf_bits(sr[1]) << 16);
        spk[2 * i + 1] = f2bf_bits(sr[2]) | (f2bf_bits(sr[3]) << 16);
    }

    // codes for a given t live in lanes {t, t+16, t+32, t+48}
    T1 += __shfl_xor(T1, 16); T1 += __shfl_xor(T1, 32);
    T2 += __shfl_xor(T2, 16); T2 += __shfl_xor(T2, 32);
    Zg += __shfl_xor(Zg, 16); Zg += __shfl_xor(Zg, 32);

    // KL(t) = sum_m p*(logp + logM) = T2/T1 - ln(T1) + ln(M)  (accurate logf)
    float klw = T2 / T1 - logf(T1) + LOG_M;
    klw += __shfl_xor(klw, 1);  klw += __shfl_xor(klw, 2);
    klw += __shfl_xor(klw, 4);  klw += __shfl_xor(klw, 8);
    klw += __shfl_xor(klw, 16); klw += __shfl_xor(klw, 32);
    if (lane == 0) atomicAdd(kl_g, 0.25f * klw);   // each t counted 4x (quad dup)

    const float invZ = 1.0f / Zg;   // per-t (all quads of this t agree)

    // ---- GEMM2: Q^T[d][t] = W^T @ S_un, K=512 in 16 chunks of 32 ----
    floatx4 C2[4];
    #pragma unroll
    for (int dt = 0; dt < 4; ++dt) C2[dt] = 0.0f;

    #pragma unroll
    for (int kk = 0; kk < 16; ++kk) {
        #pragma unroll
        for (int ii = 0; ii < 2; ++ii) {
            const int i = 2 * kk + ii;   // m = 16*i + 4*q + r
            uint2 pk;
            pk.x = spk[2 * i];
            pk.y = spk[2 * i + 1];
            // stage bf16 samples into wave-private LDS: sbuf[t][m-32kk]
            *(uint2*)&sbuf[w][ln][16 * ii + 4 * q] = pk;
            // avg_probs contribution (normalized): reduce over this wave's 16 t's
            float v0 = bf2f(pk.x & 0xffffu) * invZ;
            float v1 = bf2f(pk.x >> 16)     * invZ;
            float v2 = bf2f(pk.y & 0xffffu) * invZ;
            float v3 = bf2f(pk.y >> 16)     * invZ;
            v0 += __shfl_xor(v0,1); v0 += __shfl_xor(v0,2); v0 += __shfl_xor(v0,4); v0 += __shfl_xor(v0,8);
            v1 += __shfl_xor(v1,1); v1 += __shfl_xor(v1,2); v1 += __shfl_xor(v1,4); v1 += __shfl_xor(v1,8);
            v2 += __shfl_xor(v2,1); v2 += __shfl_xor(v2,2); v2 += __shfl_xor(v2,4); v2 += __shfl_xor(v2,8);
            v3 += __shfl_xor(v3,1); v3 += __shfl_xor(v3,2); v3 += __shfl_xor(v3,4); v3 += __shfl_xor(v3,8);
            if (ln == 0) {
                atomicAdd(&avg_lds[16*i + 4*q + 0], v0);
                atomicAdd(&avg_lds[16*i + 4*q + 1], v1);
                atomicAdd(&avg_lds[16*i + 4*q + 2], v2);
                atomicAdd(&avg_lds[16*i + 4*q + 3], v3);
            }
        }
        // cross-lane LDS RAW within the wave: drain DS queue before frag read
        __asm__ volatile("s_waitcnt lgkmcnt(0)" ::: "memory");
        // B-frag: B[k = q*8+j][n = ln] = S[32kk + q*8+j][t]
        bf16x8 sb = *(const bf16x8*)&sbuf[w][ln][8 * q];
        #pragma unroll
        for (int dt = 0; dt < 4; ++dt) {
            // A-frag: A[d = 16dt+ln][k = 32kk + q*8+j] = W^T (m-contiguous)
            bf16x8 a = *(const bf16x8*)(WTbf + (size_t)(16 * dt + ln) * 512 + 32 * kk + 8 * q);
            C2[dt] = __builtin_amdgcn_mfma_f32_16x16x32_bf16(a, sb, C2[dt], 0, 0, 0);
        }
    }

    // ---- epilogue: normalize (per-t invZ) and store quantized ----
    // lane holds d = 16*dt + 4*q + r at its t
    float* op = out + ((size_t)(b * 4096 + tg)) * 64 + 4 * q;
    #pragma unroll
    for (int dt = 0; dt < 4; ++dt) {
        floatx4 c = C2[dt];
        c[0] *= invZ; c[1] *= invZ; c[2] *= invZ; c[3] *= invZ;
        *(floatx4*)(op + 16 * dt) = c;
    }

    __syncthreads();
    atomicAdd(&avg_g[tid],       avg_lds[tid]);
    atomicAdd(&avg_g[tid + 256], avg_lds[tid + 256]);
}

// ---------------- finalize: KL mean + perplexity ----------------
__global__ void vq_fin(const float* __restrict__ avg_g, const float* __restrict__ kl_g,
                       float* __restrict__ out)
{
    const int lane = threadIdx.x;   // 64 threads
    float acc = 0.f;
    #pragma unroll
    for (int k = 0; k < 8; ++k) {
        float a = avg_g[lane * 8 + k] * (1.0f / 131072.0f);
        acc += a * logf(a + 1e-10f);
    }
    acc += __shfl_xor(acc, 1);  acc += __shfl_xor(acc, 2);
    acc += __shfl_xor(acc, 4);  acc += __shfl_xor(acc, 8);
    acc += __shfl_xor(acc, 16); acc += __shfl_xor(acc, 32);
    if (lane == 0) {
        out[8388608] = kl_g[0] * (1.0f / 32.0f);   // mean over B
        out[8388609] = expf(-acc);
    }
}

extern "C" void kernel_launch(void* const* d_in, const int* in_sizes, int n_in,
                              void* d_out, int out_size, void* d_ws, size_t ws_size,
                              hipStream_t stream)
{
    const float* x = (const float*)d_in[0];   // (32, 64, 4096)
    const float* u = (const float*)d_in[1];   // (32, 4096, 512)
    const float* W = (const float*)d_in[2];   // (512, 64)
    float* out = (float*)d_out;

    char* ws = (char*)d_ws;
    unsigned short* Wbf  = (unsigned short*)(ws);            // 65536 B
    unsigned short* WTbf = (unsigned short*)(ws + 65536);    // 65536 B
    float* wn2   = (float*)(ws + 131072);                    // 2048 B
    float* avg_g = (float*)(ws + 133120);                    // 2048 B
    float* kl_g  = (float*)(ws + 135168);                    // 4 B

    // zero the accumulators (ws is poisoned to 0xAA before every launch)
    (void)hipMemsetAsync(ws + 133120, 0, 2048 + 64, stream);

    vq_prep<<<dim3(2),    dim3(256), 0, stream>>>(W, Wbf, WTbf, wn2);
    vq_main<<<dim3(2048), dim3(256), 0, stream>>>(x, u, Wbf, WTbf, wn2, out, avg_g, kl_g);
    vq_fin <<<dim3(1),    dim3(64),  0, stream>>>(avg_g, kl_g, out);
}